// Round 7
// baseline (1247.904 us; speedup 1.0000x reference)
//
#include <hip/hip_runtime.h>
#include <hip/hip_fp16.h>

// GCN: fully fused single-launch kernel with software grid barriers.
// Phases: init/Wsplit | p1 bucket-bin | p2 CSR | 3x(gemm -> agg) | pool
#define NN 10000
#define NE 640000
#define NG 64
#define CAP 128   // slot capacity per dst (slot deg holds zero-row pad)
#define NB 625    // buckets of 16 dst nodes
#define BCAP 1280 // per-bucket edge capacity
#define GRIDSZ 1024
#define NBAR 9

typedef _Float16 f16x8 __attribute__((ext_vector_type(8)));
typedef float f32x4 __attribute__((ext_vector_type(4)));

union ShMem {
    int hist[NB];                                  // p1
    struct { int buf[16 * CAP]; int cnt[16]; } p2; // p2
    float sm[256];                                 // pool
};

// Software grid barrier: counting, one fresh slot per barrier (zeroed host-side
// each launch). Device-scope atomics handle cross-XCD L2 non-coherence;
// threadfence gives release/acquire for the surrounding plain loads/stores.
__device__ __forceinline__ void gsync(int* bar, int id) {
    __syncthreads();
    if (threadIdx.x == 0) {
        __threadfence();                       // release my block's writes
        atomicAdd(&bar[id], 1);
        while (atomicAdd(&bar[id], 0) < GRIDSZ) __builtin_amdgcn_s_sleep(16);
        __threadfence();                       // acquire others' writes
    }
    __syncthreads();
}

// ---------------- GEMM phase (MFMA, split fp16) ----------------
// g16[r][c] = fp16( dis[r] * (act(in)[r] @ W)[:,c] ); rows 10000..10015 zero pad.
__device__ __forceinline__ void gemm_phase(const float* __restrict__ in,
                                           const __half* __restrict__ whT,
                                           const __half* __restrict__ wlT,
                                           const int* __restrict__ deg,
                                           __half* __restrict__ g16, int relu,
                                           int bid, int t) {
    const _Float16* wh = (const _Float16*)whT;
    const _Float16* wl = (const _Float16*)wlT;
    for (int s = bid; s < 626; s += GRIDSZ) {
        int w = t >> 6, l = t & 63;
        int rw = (s % 313) * 32 + (w & 1) * 16;
        int cw = (s / 313) * 64 + (w >> 1) * 32;
        int lr = l & 15, lg = l >> 4;
        int row = rw + lr;
        int rclamp = min(row, NN - 1);
        f32x4 acc0 = {0.f, 0.f, 0.f, 0.f}, acc1 = {0.f, 0.f, 0.f, 0.f};
#pragma unroll
        for (int ks = 0; ks < 4; ks++) {
            int kb = ks * 32 + lg * 8;
            float4 xa = *(const float4*)&in[rclamp * 128 + kb];
            float4 xb = *(const float4*)&in[rclamp * 128 + kb + 4];
            float x0 = xa.x, x1 = xa.y, x2 = xa.z, x3 = xa.w;
            float x4 = xb.x, x5 = xb.y, x6 = xb.z, x7 = xb.w;
            if (relu) {
                x0 = fmaxf(x0, 0.f); x1 = fmaxf(x1, 0.f); x2 = fmaxf(x2, 0.f); x3 = fmaxf(x3, 0.f);
                x4 = fmaxf(x4, 0.f); x5 = fmaxf(x5, 0.f); x6 = fmaxf(x6, 0.f); x7 = fmaxf(x7, 0.f);
            }
            f16x8 ah, al;
            ah[0] = (_Float16)x0; al[0] = (_Float16)(x0 - (float)ah[0]);
            ah[1] = (_Float16)x1; al[1] = (_Float16)(x1 - (float)ah[1]);
            ah[2] = (_Float16)x2; al[2] = (_Float16)(x2 - (float)ah[2]);
            ah[3] = (_Float16)x3; al[3] = (_Float16)(x3 - (float)ah[3]);
            ah[4] = (_Float16)x4; al[4] = (_Float16)(x4 - (float)ah[4]);
            ah[5] = (_Float16)x5; al[5] = (_Float16)(x5 - (float)ah[5]);
            ah[6] = (_Float16)x6; al[6] = (_Float16)(x6 - (float)ah[6]);
            ah[7] = (_Float16)x7; al[7] = (_Float16)(x7 - (float)ah[7]);
            int c0 = cw + lr;
            f16x8 bh0 = *(const f16x8*)&wh[c0 * 128 + kb];
            f16x8 bl0 = *(const f16x8*)&wl[c0 * 128 + kb];
            f16x8 bh1 = *(const f16x8*)&wh[(c0 + 16) * 128 + kb];
            f16x8 bl1 = *(const f16x8*)&wl[(c0 + 16) * 128 + kb];
            acc0 = __builtin_amdgcn_mfma_f32_16x16x32_f16(ah, bh0, acc0, 0, 0, 0);
            acc1 = __builtin_amdgcn_mfma_f32_16x16x32_f16(ah, bh1, acc1, 0, 0, 0);
            acc0 = __builtin_amdgcn_mfma_f32_16x16x32_f16(al, bh0, acc0, 0, 0, 0);
            acc1 = __builtin_amdgcn_mfma_f32_16x16x32_f16(al, bh1, acc1, 0, 0, 0);
            acc0 = __builtin_amdgcn_mfma_f32_16x16x32_f16(ah, bl0, acc0, 0, 0, 0);
            acc1 = __builtin_amdgcn_mfma_f32_16x16x32_f16(ah, bl1, acc1, 0, 0, 0);
        }
#pragma unroll
        for (int reg = 0; reg < 4; reg++) {
            int r = rw + lg * 4 + reg;
            int c = cw + lr;
            if (r < NN) {
                float d = rsqrtf((float)deg[r] + 1.0f);
                g16[r * 128 + c] = __float2half(acc0[reg] * d);
                g16[r * 128 + c + 16] = __float2half(acc1[reg] * d);
            } else {  // zero pad rows 10000..10015
                g16[r * 128 + c] = __float2half(0.f);
                g16[r * 128 + c + 16] = __float2half(0.f);
            }
        }
    }
}

// ---------------- aggregation phase: dual-edge half-wave ----------------
__device__ __forceinline__ void accp(uint2 v, float2& p, float2& q) {
    float2 f0 = __half22float2(*(__half2*)&v.x);
    float2 f1 = __half22float2(*(__half2*)&v.y);
    p.x += f0.x; p.y += f0.y; q.x += f1.x; q.y += f1.y;
}

__device__ __forceinline__ void agg_phase(const __half* __restrict__ g16,
                                          const float* __restrict__ bias,
                                          const int* __restrict__ deg,
                                          const int* __restrict__ csrc,
                                          float* __restrict__ out,
                                          int bid, int t) {
    int w = t >> 6, l = t & 63;
    int half = l >> 5, li = l & 31;
    int co = li * 4;  // column offset in halfs
    for (int i = bid * 4 + w; i < NN; i += GRIDSZ * 4) {
        int dgi = __builtin_amdgcn_readfirstlane(deg[i]);
        int n = min(dgi, CAP - 1);
        int np = (n + 1) & ~1;  // even; slot n = pad when n odd
        float2 A0 = {0.f, 0.f}, A1 = {0.f, 0.f};
        float2 B0 = {0.f, 0.f}, B1 = {0.f, 0.f};
        if (half == 0) {  // self contribution
            uint2 sv = *(const uint2*)&g16[i * 128 + co];
            float2 f0 = __half22float2(*(__half2*)&sv.x);
            float2 f1 = __half22float2(*(__half2*)&sv.y);
            A0 = f0; A1 = f1;
        }
        const int* cp = &csrc[i << 7];
        for (int base = 0; base < np; base += 64) {
            int m = np - base;
            if (m > 64) m = 64;  // even
            int myedge = (l < m) ? cp[base + l] : NN;
            int pairs = m >> 1;
            int j = 0;
            for (; j + 8 <= pairs; j += 8) {
                int r0 = __shfl(myedge, 2 * j + half);
                int r1 = __shfl(myedge, 2 * j + 2 + half);
                int r2 = __shfl(myedge, 2 * j + 4 + half);
                int r3 = __shfl(myedge, 2 * j + 6 + half);
                int r4 = __shfl(myedge, 2 * j + 8 + half);
                int r5 = __shfl(myedge, 2 * j + 10 + half);
                int r6 = __shfl(myedge, 2 * j + 12 + half);
                int r7 = __shfl(myedge, 2 * j + 14 + half);
                uint2 v0 = *(const uint2*)&g16[r0 * 128 + co];
                uint2 v1 = *(const uint2*)&g16[r1 * 128 + co];
                uint2 v2 = *(const uint2*)&g16[r2 * 128 + co];
                uint2 v3 = *(const uint2*)&g16[r3 * 128 + co];
                uint2 v4 = *(const uint2*)&g16[r4 * 128 + co];
                uint2 v5 = *(const uint2*)&g16[r5 * 128 + co];
                uint2 v6 = *(const uint2*)&g16[r6 * 128 + co];
                uint2 v7 = *(const uint2*)&g16[r7 * 128 + co];
                accp(v0, A0, A1); accp(v1, B0, B1);
                accp(v2, A0, A1); accp(v3, B0, B1);
                accp(v4, A0, A1); accp(v5, B0, B1);
                accp(v6, A0, A1); accp(v7, B0, B1);
            }
            for (; j < pairs; j++) {
                int r = __shfl(myedge, 2 * j + half);
                uint2 v = *(const uint2*)&g16[r * 128 + co];
                accp(v, A0, A1);
            }
        }
        A0.x += B0.x; A0.y += B0.y; A1.x += B1.x; A1.y += B1.y;
        A0.x += __shfl_xor(A0.x, 32);
        A0.y += __shfl_xor(A0.y, 32);
        A1.x += __shfl_xor(A1.x, 32);
        A1.y += __shfl_xor(A1.y, 32);
        if (half == 0) {
            float di = rsqrtf((float)dgi + 1.0f);
            float4 bb = *(const float4*)&bias[co];
            float4 o;
            o.x = di * A0.x + bb.x;
            o.y = di * A0.y + bb.y;
            o.z = di * A1.x + bb.z;
            o.w = di * A1.y + bb.w;
            *(float4*)&out[i * 128 + co] = o;
        }
    }
}

// ---------------- the fused kernel (plain launch + software barriers) ----------------
__global__ __launch_bounds__(256, 4) void k_fused(
    const float* __restrict__ x, const int* __restrict__ ei, const int* __restrict__ batch,
    const float* __restrict__ W0, const float* __restrict__ b0,
    const float* __restrict__ W1, const float* __restrict__ b1,
    const float* __restrict__ W2, const float* __restrict__ b2,
    float* __restrict__ out,
    int* deg, int* gstart, int* bcur, int* bar, int* csrc, __half* g16, float* abuf,
    int* pk, __half* wh, __half* wl)
{
    __shared__ ShMem sh;
    int bid = blockIdx.x, t = threadIdx.x;

    // ---- phase A: init gstart/bcur + W split/transpose ----
    if (bid < 40) {
        int i = bid * 256 + t;
        if (i < NB) bcur[i] = 0;
        if (i < NN) {
            int b = batch[i];
            int prev = (i == 0) ? -1 : batch[i - 1];
            for (int g = prev + 1; g <= b; g++) gstart[g] = i;
            if (i == NN - 1)
                for (int g = b + 1; g <= NG; g++) gstart[g] = NN;
        }
    } else if (bid < 232) {
        int wid = bid - 40;             // 0..191
        int z = wid >> 6;               // which W
        int q = (wid & 63) * 256 + t;   // 0..16383
        int c = q >> 7, k = q & 127;
        const float* W = (z == 0) ? W0 : (z == 1) ? W1 : W2;
        float v = W[k * 128 + c];
        __half h = __float2half(v);
        __half lo = __float2half(v - __half2float(h));
        wh[z * 16384 + c * 128 + k] = h;   // transposed [c][k]
        wl[z * 16384 + c * 128 + k] = lo;
    }
    gsync(bar, 0);

    // ---- phase B: p1 coarse-bin (blocks 0..156, 4096 edges each) ----
    if (bid < 157) {
        for (int q = t; q < NB; q += 256) sh.hist[q] = 0;
        __syncthreads();
        int4 s4[4], d4[4];
        int ebase = bid * 4096;
#pragma unroll
        for (int q = 0; q < 4; q++) {
            int e = ebase + q * 1024 + t * 4;
            if (e < NE) {
                s4[q] = *(const int4*)&ei[e];
                d4[q] = *(const int4*)&ei[NE + e];
                atomicAdd(&sh.hist[d4[q].x >> 4], 1);
                atomicAdd(&sh.hist[d4[q].y >> 4], 1);
                atomicAdd(&sh.hist[d4[q].z >> 4], 1);
                atomicAdd(&sh.hist[d4[q].w >> 4], 1);
            }
        }
        __syncthreads();
        for (int q = t; q < NB; q += 256) {
            int h = sh.hist[q];
            sh.hist[q] = (h > 0) ? atomicAdd(&bcur[q], h) : 0;
        }
        __syncthreads();
#pragma unroll
        for (int q = 0; q < 4; q++) {
            int e = ebase + q * 1024 + t * 4;
            if (e < NE) {
                int b0i = d4[q].x >> 4, b1i = d4[q].y >> 4, b2i = d4[q].z >> 4, b3i = d4[q].w >> 4;
                int r0 = atomicAdd(&sh.hist[b0i], 1);
                int r1 = atomicAdd(&sh.hist[b1i], 1);
                int r2 = atomicAdd(&sh.hist[b2i], 1);
                int r3 = atomicAdd(&sh.hist[b3i], 1);
                if (r0 < BCAP) pk[b0i * BCAP + r0] = s4[q].x | ((d4[q].x & 15) << 14);
                if (r1 < BCAP) pk[b1i * BCAP + r1] = s4[q].y | ((d4[q].y & 15) << 14);
                if (r2 < BCAP) pk[b2i * BCAP + r2] = s4[q].z | ((d4[q].z & 15) << 14);
                if (r3 < BCAP) pk[b3i * BCAP + r3] = s4[q].w | ((d4[q].w & 15) << 14);
            }
        }
    }
    gsync(bar, 1);

    // ---- phase C: p2 fine CSR (blocks 0..624) ----
    if (bid < NB) {
        if (t < 16) sh.p2.cnt[t] = 0;
        __syncthreads();
        int n = bcur[bid];
        if (n > BCAP) n = BCAP;
        const int* pb = &pk[bid * BCAP];
        for (int i = t; i < n; i += 256) {
            int v = pb[i];
            int nd = v >> 14;
            int slot = atomicAdd(&sh.p2.cnt[nd], 1);
            if (slot < CAP) sh.p2.buf[(nd << 7) + slot] = v & 0x3FFF;
        }
        __syncthreads();
        int node0 = bid << 4;
        if (t < 16) {
            int c = sh.p2.cnt[t];
            deg[node0 + t] = c;
            sh.p2.buf[(t << 7) + min(c, CAP - 1)] = NN;  // pad -> zero row
        }
        __syncthreads();
        int4* d4 = (int4*)&csrc[node0 << 7];
        const int4* s4 = (const int4*)sh.p2.buf;
#pragma unroll
        for (int i = 0; i < 2; i++) d4[t + i * 256] = s4[t + i * 256];
    }
    gsync(bar, 2);

    // ---- layers ----
    gemm_phase(x, wh, wl, deg, g16, 0, bid, t);
    gsync(bar, 3);
    agg_phase(g16, b0, deg, csrc, abuf, bid, t);
    gsync(bar, 4);
    gemm_phase(abuf, wh + 16384, wl + 16384, deg, g16, 1, bid, t);
    gsync(bar, 5);
    agg_phase(g16, b1, deg, csrc, abuf, bid, t);
    gsync(bar, 6);
    gemm_phase(abuf, wh + 32768, wl + 32768, deg, g16, 1, bid, t);
    gsync(bar, 7);
    agg_phase(g16, b2, deg, csrc, abuf, bid, t);
    gsync(bar, 8);

    // ---- phase J: mean pool (blocks 0..63) ----
    if (bid < NG) {
        int g = bid;
        int s = gstart[g], e = gstart[g + 1];
        int c = t & 127, hf = t >> 7;
        float acc = 0.f;
        for (int n = s + hf; n < e; n += 2) acc += abuf[n * 128 + c];
        sh.sm[t] = acc;
        __syncthreads();
        if (hf == 0) {
            float cnt = (float)max(e - s, 1);
            out[g * 128 + c] = (sh.sm[c] + sh.sm[128 + c]) / cnt;
        }
    }
}

extern "C" void kernel_launch(void* const* d_in, const int* in_sizes, int n_in,
                              void* d_out, int out_size, void* d_ws, size_t ws_size,
                              hipStream_t stream) {
    const float* x     = (const float*)d_in[0];
    const int*   ei    = (const int*)d_in[1];
    const int*   batch = (const int*)d_in[2];
    const float* W0 = (const float*)d_in[3];
    const float* b0 = (const float*)d_in[4];
    const float* W1 = (const float*)d_in[5];
    const float* b1 = (const float*)d_in[6];
    const float* W2 = (const float*)d_in[7];
    const float* b2 = (const float*)d_in[8];
    float* out = (float*)d_out;

    // workspace layout (float units)
    float* ws    = (float*)d_ws;
    int*   deg   = (int*)ws;                   // 10000 ints
    int*   gstart= (int*)(ws + 10240);         // 65 ints
    int*   bcur  = (int*)(ws + 10320);         // 625 ints
    int*   bar   = (int*)(ws + 10952);         // NBAR ints (barrier counters)
    int*   csrc  = (int*)(ws + 11008);         // 10000*128 ints (5.12 MB)
    __half* g16  = (__half*)(ws + 1291008);    // 10016*128 fp16 (incl. 16 zero pad rows)
    float* abuf  = ws + 1932032;               // 10000*128 f32 (5.12 MB)
    int*   pk    = (int*)(ws + 1932032);       // NB*BCAP ints (3.2 MB) — aliases abuf (dead before agg0)
    __half* wh   = (__half*)(ws + 3212032);    // 3*128*128 fp16 hi, [c][k]
    __half* wlo  = (__half*)(ws + 3236608);    // 3*128*128 fp16 lo

    hipMemsetAsync(bar, 0, NBAR * sizeof(int), stream);
    k_fused<<<GRIDSZ, 256, 0, stream>>>(
        x, ei, batch, W0, b0, W1, b1, W2, b2, out,
        deg, gstart, bcur, bar, csrc, g16, abuf, pk, wh, wlo);
}

// Round 8
// 358.811 us; speedup vs baseline: 3.4779x; 3.4779x over previous
//
#include <hip/hip_runtime.h>
#include <hip/hip_fp16.h>

// GCN: 3x (MFMA split-f16 GEMM -> dual-edge half-wave aggregation) + mean pool.
// DIAGNOSTIC ROUND: layer-0 gemm/agg run with ITER-repeat to surface in rocprof top-5.
#define NN 10000
#define NE 640000
#define NG 64
#define CAP 128   // fixed slot capacity per dst (slot deg holds zero-row pad)
#define NB 625    // coarse buckets of 16 dst nodes
#define BCAP 1280 // per-bucket edge capacity

typedef _Float16 f16x8 __attribute__((ext_vector_type(8)));
typedef float f32x4 __attribute__((ext_vector_type(4)));

// ---------------- init: graph boundaries + zero cursors + W split/transpose ----------------
__global__ __launch_bounds__(256) void k_init(const int* __restrict__ batch,
                                              int* __restrict__ gstart,
                                              int* __restrict__ bcur,
                                              const float* __restrict__ W0,
                                              const float* __restrict__ W1,
                                              const float* __restrict__ W2,
                                              __half* __restrict__ wh,
                                              __half* __restrict__ wl) {
    int bid = blockIdx.x, t = threadIdx.x;
    if (bid < 40) {
        int i = bid * 256 + t;
        if (i < NB) bcur[i] = 0;
        if (i >= NN) return;
        int b = batch[i];
        int prev = (i == 0) ? -1 : batch[i - 1];
        for (int g = prev + 1; g <= b; g++) gstart[g] = i;
        if (i == NN - 1)
            for (int g = b + 1; g <= NG; g++) gstart[g] = NN;
        return;
    }
    int wid = bid - 40;             // 0..191
    int z = wid >> 6;               // which W
    int q = (wid & 63) * 256 + t;   // 0..16383
    int c = q >> 7, k = q & 127;
    const float* W = (z == 0) ? W0 : (z == 1) ? W1 : W2;
    float v = W[k * 128 + c];
    __half h = __float2half(v);
    __half lo = __float2half(v - __half2float(h));
    wh[z * 16384 + c * 128 + k] = h;   // transposed [c][k]
    wl[z * 16384 + c * 128 + k] = lo;
}

// ---------------- P1: coarse-bin edges (LDS histogram, 1 global atomic per block-bucket) ----------------
__global__ __launch_bounds__(256) void k_p1(const int* __restrict__ ei,
                                            int* __restrict__ bcur,
                                            int* __restrict__ pk) {
    __shared__ int hist[NB];
    int t = threadIdx.x;
    for (int q = t; q < NB; q += 256) hist[q] = 0;
    __syncthreads();

    int4 s4[4], d4[4];
    int ebase = blockIdx.x * 4096;
#pragma unroll
    for (int q = 0; q < 4; q++) {
        int e = ebase + q * 1024 + t * 4;
        if (e < NE) {
            s4[q] = *(const int4*)&ei[e];
            d4[q] = *(const int4*)&ei[NE + e];
            atomicAdd(&hist[d4[q].x >> 4], 1);
            atomicAdd(&hist[d4[q].y >> 4], 1);
            atomicAdd(&hist[d4[q].z >> 4], 1);
            atomicAdd(&hist[d4[q].w >> 4], 1);
        }
    }
    __syncthreads();

    for (int q = t; q < NB; q += 256) {
        int h = hist[q];
        hist[q] = (h > 0) ? atomicAdd(&bcur[q], h) : 0;
    }
    __syncthreads();

#pragma unroll
    for (int q = 0; q < 4; q++) {
        int e = ebase + q * 1024 + t * 4;
        if (e < NE) {
            int b0 = d4[q].x >> 4, b1 = d4[q].y >> 4, b2 = d4[q].z >> 4, b3 = d4[q].w >> 4;
            int r0 = atomicAdd(&hist[b0], 1);
            int r1 = atomicAdd(&hist[b1], 1);
            int r2 = atomicAdd(&hist[b2], 1);
            int r3 = atomicAdd(&hist[b3], 1);
            if (r0 < BCAP) pk[b0 * BCAP + r0] = s4[q].x | ((d4[q].x & 15) << 14);
            if (r1 < BCAP) pk[b1 * BCAP + r1] = s4[q].y | ((d4[q].y & 15) << 14);
            if (r2 < BCAP) pk[b2 * BCAP + r2] = s4[q].z | ((d4[q].z & 15) << 14);
            if (r3 < BCAP) pk[b3 * BCAP + r3] = s4[q].w | ((d4[q].w & 15) << 14);
        }
    }
}

// ---------------- P2: per-bucket fine CSR in LDS, pad slot deg with zero-row index ----------------
__global__ __launch_bounds__(256) void k_p2(const int* __restrict__ bcur,
                                            const int* __restrict__ pk,
                                            int* __restrict__ deg,
                                            int* __restrict__ csrc) {
    __shared__ int buf[16 * CAP];  // 8 KB
    __shared__ int cnt[16];
    int b = blockIdx.x, t = threadIdx.x;
    if (t < 16) cnt[t] = 0;
    __syncthreads();

    int n = bcur[b];
    if (n > BCAP) n = BCAP;
    const int* pb = &pk[b * BCAP];
    for (int i = t; i < n; i += 256) {
        int v = pb[i];
        int nd = v >> 14;
        int slot = atomicAdd(&cnt[nd], 1);
        if (slot < CAP) buf[(nd << 7) + slot] = v & 0x3FFF;
    }
    __syncthreads();

    int node0 = b << 4;
    if (t < 16) {
        int c = cnt[t];
        deg[node0 + t] = c;
        buf[(t << 7) + min(c, CAP - 1)] = NN;  // pad -> zero row
    }
    __syncthreads();

    int4* d4 = (int4*)&csrc[node0 << 7];
    const int4* s4 = (const int4*)buf;
#pragma unroll
    for (int i = 0; i < 2; i++) d4[t + i * 256] = s4[t + i * 256];
}

// ---------------- GEMM (MFMA, split fp16), ITER-repeatable for profiling ----------------
template <int ITER>
__global__ __launch_bounds__(256) void k_gemm(const float* __restrict__ in,
                                              const __half* __restrict__ whT,
                                              const __half* __restrict__ wlT,
                                              const int* __restrict__ deg,
                                              __half* __restrict__ g16, int relu) {
    int t = threadIdx.x;
    int w = t >> 6, l = t & 63;
    int rw = blockIdx.x * 32 + (w & 1) * 16;
    int cw = blockIdx.y * 64 + (w >> 1) * 32;
    int lr = l & 15, lg = l >> 4;
    int row = rw + lr;
    int rclamp = min(row, NN - 1);
    const _Float16* wh = (const _Float16*)whT;
    const _Float16* wl = (const _Float16*)wlT;
    for (int it = 0; it < ITER; ++it) {
        asm volatile("" ::: "memory");  // force loads to re-issue each repeat
        f32x4 acc0 = {0.f, 0.f, 0.f, 0.f}, acc1 = {0.f, 0.f, 0.f, 0.f};
#pragma unroll
        for (int ks = 0; ks < 4; ks++) {
            int kb = ks * 32 + lg * 8;
            float4 xa = *(const float4*)&in[rclamp * 128 + kb];
            float4 xb = *(const float4*)&in[rclamp * 128 + kb + 4];
            float x0 = xa.x, x1 = xa.y, x2 = xa.z, x3 = xa.w;
            float x4 = xb.x, x5 = xb.y, x6 = xb.z, x7 = xb.w;
            if (relu) {
                x0 = fmaxf(x0, 0.f); x1 = fmaxf(x1, 0.f); x2 = fmaxf(x2, 0.f); x3 = fmaxf(x3, 0.f);
                x4 = fmaxf(x4, 0.f); x5 = fmaxf(x5, 0.f); x6 = fmaxf(x6, 0.f); x7 = fmaxf(x7, 0.f);
            }
            f16x8 ah, al;
            ah[0] = (_Float16)x0; al[0] = (_Float16)(x0 - (float)ah[0]);
            ah[1] = (_Float16)x1; al[1] = (_Float16)(x1 - (float)ah[1]);
            ah[2] = (_Float16)x2; al[2] = (_Float16)(x2 - (float)ah[2]);
            ah[3] = (_Float16)x3; al[3] = (_Float16)(x3 - (float)ah[3]);
            ah[4] = (_Float16)x4; al[4] = (_Float16)(x4 - (float)ah[4]);
            ah[5] = (_Float16)x5; al[5] = (_Float16)(x5 - (float)ah[5]);
            ah[6] = (_Float16)x6; al[6] = (_Float16)(x6 - (float)ah[6]);
            ah[7] = (_Float16)x7; al[7] = (_Float16)(x7 - (float)ah[7]);
            int c0 = cw + lr;
            f16x8 bh0 = *(const f16x8*)&wh[c0 * 128 + kb];
            f16x8 bl0 = *(const f16x8*)&wl[c0 * 128 + kb];
            f16x8 bh1 = *(const f16x8*)&wh[(c0 + 16) * 128 + kb];
            f16x8 bl1 = *(const f16x8*)&wl[(c0 + 16) * 128 + kb];
            acc0 = __builtin_amdgcn_mfma_f32_16x16x32_f16(ah, bh0, acc0, 0, 0, 0);
            acc1 = __builtin_amdgcn_mfma_f32_16x16x32_f16(ah, bh1, acc1, 0, 0, 0);
            acc0 = __builtin_amdgcn_mfma_f32_16x16x32_f16(al, bh0, acc0, 0, 0, 0);
            acc1 = __builtin_amdgcn_mfma_f32_16x16x32_f16(al, bh1, acc1, 0, 0, 0);
            acc0 = __builtin_amdgcn_mfma_f32_16x16x32_f16(ah, bl0, acc0, 0, 0, 0);
            acc1 = __builtin_amdgcn_mfma_f32_16x16x32_f16(ah, bl1, acc1, 0, 0, 0);
        }
        if (it == ITER - 1) {
#pragma unroll
            for (int reg = 0; reg < 4; reg++) {
                int r = rw + lg * 4 + reg;
                int c = cw + lr;
                if (r < NN) {
                    float d = rsqrtf((float)deg[r] + 1.0f);
                    g16[r * 128 + c] = __float2half(acc0[reg] * d);
                    g16[r * 128 + c + 16] = __float2half(acc1[reg] * d);
                } else {  // zero pad rows 10000..10015
                    g16[r * 128 + c] = __float2half(0.f);
                    g16[r * 128 + c + 16] = __float2half(0.f);
                }
            }
        } else {
            asm volatile("" :: "v"(acc0[0]), "v"(acc0[1]), "v"(acc0[2]), "v"(acc0[3]),
                               "v"(acc1[0]), "v"(acc1[1]), "v"(acc1[2]), "v"(acc1[3]));
        }
    }
}

// ---------------- aggregation: dual-edge half-wave, ITER-repeatable for profiling ----------------
__device__ __forceinline__ void accp(uint2 v, float2& p, float2& q) {
    float2 f0 = __half22float2(*(__half2*)&v.x);
    float2 f1 = __half22float2(*(__half2*)&v.y);
    p.x += f0.x; p.y += f0.y; q.x += f1.x; q.y += f1.y;
}

template <int ITER>
__global__ __launch_bounds__(256) void k_agg(const __half* __restrict__ g16,
                                             const float* __restrict__ bias,
                                             const int* __restrict__ deg,
                                             const int* __restrict__ csrc,
                                             float* __restrict__ out) {
    int wid = blockIdx.x * 4 + (threadIdx.x >> 6);
    int l = threadIdx.x & 63;
    if (wid >= NN) return;
    int i = wid;
    int dgi = __builtin_amdgcn_readfirstlane(deg[i]);
    int n = min(dgi, CAP - 1);
    int np = (n + 1) & ~1;      // even; slot n = pad when n odd
    int half = l >> 5, li = l & 31;
    int co = li * 4;            // column offset in halfs
    const int* cp = &csrc[i << 7];
    for (int it = 0; it < ITER; ++it) {
        asm volatile("" ::: "memory");  // force loads to re-issue each repeat
        float2 A0 = {0.f, 0.f}, A1 = {0.f, 0.f};
        float2 B0 = {0.f, 0.f}, B1 = {0.f, 0.f};
        if (half == 0) {  // self contribution
            uint2 sv = *(const uint2*)&g16[i * 128 + co];
            float2 f0 = __half22float2(*(__half2*)&sv.x);
            float2 f1 = __half22float2(*(__half2*)&sv.y);
            A0 = f0; A1 = f1;
        }
        for (int base = 0; base < np; base += 64) {
            int m = np - base;
            if (m > 64) m = 64;           // even
            int myedge = (l < m) ? cp[base + l] : NN;
            int pairs = m >> 1;
            int j = 0;
            for (; j + 8 <= pairs; j += 8) {
                int r0 = __shfl(myedge, 2 * j + half);
                int r1 = __shfl(myedge, 2 * j + 2 + half);
                int r2 = __shfl(myedge, 2 * j + 4 + half);
                int r3 = __shfl(myedge, 2 * j + 6 + half);
                int r4 = __shfl(myedge, 2 * j + 8 + half);
                int r5 = __shfl(myedge, 2 * j + 10 + half);
                int r6 = __shfl(myedge, 2 * j + 12 + half);
                int r7 = __shfl(myedge, 2 * j + 14 + half);
                uint2 v0 = *(const uint2*)&g16[r0 * 128 + co];
                uint2 v1 = *(const uint2*)&g16[r1 * 128 + co];
                uint2 v2 = *(const uint2*)&g16[r2 * 128 + co];
                uint2 v3 = *(const uint2*)&g16[r3 * 128 + co];
                uint2 v4 = *(const uint2*)&g16[r4 * 128 + co];
                uint2 v5 = *(const uint2*)&g16[r5 * 128 + co];
                uint2 v6 = *(const uint2*)&g16[r6 * 128 + co];
                uint2 v7 = *(const uint2*)&g16[r7 * 128 + co];
                accp(v0, A0, A1); accp(v1, B0, B1);
                accp(v2, A0, A1); accp(v3, B0, B1);
                accp(v4, A0, A1); accp(v5, B0, B1);
                accp(v6, A0, A1); accp(v7, B0, B1);
            }
            for (; j < pairs; j++) {
                int r = __shfl(myedge, 2 * j + half);
                uint2 v = *(const uint2*)&g16[r * 128 + co];
                accp(v, A0, A1);
            }
        }
        A0.x += B0.x; A0.y += B0.y; A1.x += B1.x; A1.y += B1.y;
        // combine the two halves (same cols, disjoint edge subsets)
        A0.x += __shfl_xor(A0.x, 32);
        A0.y += __shfl_xor(A0.y, 32);
        A1.x += __shfl_xor(A1.x, 32);
        A1.y += __shfl_xor(A1.y, 32);
        if (it == ITER - 1) {
            if (half == 0) {
                float di = rsqrtf((float)dgi + 1.0f);
                float4 bb = *(const float4*)&bias[co];
                float4 o;
                o.x = di * A0.x + bb.x;
                o.y = di * A0.y + bb.y;
                o.z = di * A1.x + bb.z;
                o.w = di * A1.y + bb.w;
                *(float4*)&out[i * 128 + co] = o;
            }
        } else {
            asm volatile("" :: "v"(A0.x), "v"(A0.y), "v"(A1.x), "v"(A1.y));
        }
    }
}

// ---------------- mean pool: one block per graph, zero atomics ----------------
__global__ __launch_bounds__(256) void k_pool(const float* __restrict__ h,
                                              const int* __restrict__ gstart,
                                              float* __restrict__ out) {
    int g = blockIdx.x;
    int s = gstart[g], e = gstart[g + 1];
    int t = threadIdx.x;
    int c = t & 127, half = t >> 7;
    float acc = 0.f;
    for (int n = s + half; n < e; n += 2) acc += h[n * 128 + c];
    __shared__ float sm[256];
    sm[t] = acc;
    __syncthreads();
    if (half == 0) {
        float cnt = (float)max(e - s, 1);
        out[g * 128 + c] = (sm[c] + sm[128 + c]) / cnt;
    }
}

extern "C" void kernel_launch(void* const* d_in, const int* in_sizes, int n_in,
                              void* d_out, int out_size, void* d_ws, size_t ws_size,
                              hipStream_t stream) {
    const float* x     = (const float*)d_in[0];
    const int*   ei    = (const int*)d_in[1];
    const int*   batch = (const int*)d_in[2];
    const float* W0 = (const float*)d_in[3];
    const float* b0 = (const float*)d_in[4];
    const float* W1 = (const float*)d_in[5];
    const float* b1 = (const float*)d_in[6];
    const float* W2 = (const float*)d_in[7];
    const float* b2 = (const float*)d_in[8];
    float* out = (float*)d_out;

    // workspace layout (float units)
    float* ws    = (float*)d_ws;
    int*   deg   = (int*)ws;                   // 10000 ints
    int*   gstart= (int*)(ws + 10240);         // 65 ints
    int*   bcur  = (int*)(ws + 10320);         // 625 ints
    int*   csrc  = (int*)(ws + 10960);         // 10000*128 ints (5.12 MB)
    __half* g16  = (__half*)(ws + 1290960);    // 10016*128 fp16 (incl. 16 zero pad rows)
    float* abuf  = ws + 1931984;               // 10000*128 f32 (5.12 MB)
    int*   pk    = (int*)(ws + 1931984);       // NB*BCAP ints (3.2 MB) — aliases abuf (dead until agg0)
    __half* wh   = (__half*)(ws + 3211984);    // 3*128*128 fp16 hi, [c][k]
    __half* wlo  = (__half*)(ws + 3236560);    // 3*128*128 fp16 lo

    k_init<<<232, 256, 0, stream>>>(batch, gstart, bcur, W0, W1, W2, wh, wlo);
    k_p1<<<157, 256, 0, stream>>>(ei, bcur, pk);
    k_p2<<<NB, 256, 0, stream>>>(bcur, pk, deg, csrc);

    dim3 ggrid(313, 2);
    // layer 0: ITER-repeated for rocprof visibility (numerics unchanged)
    k_gemm<16><<<ggrid, 256, 0, stream>>>(x, wh, wlo, deg, g16, 0);
    k_agg<5><<<2500, 256, 0, stream>>>(g16, b0, deg, csrc, abuf);
    // layer 1 (relu on input)
    k_gemm<1><<<ggrid, 256, 0, stream>>>(abuf, wh + 16384, wlo + 16384, deg, g16, 1);
    k_agg<1><<<2500, 256, 0, stream>>>(g16, b1, deg, csrc, abuf);
    // layer 2 (relu on input, no relu on output)
    k_gemm<1><<<ggrid, 256, 0, stream>>>(abuf, wh + 32768, wlo + 32768, deg, g16, 1);
    k_agg<1><<<2500, 256, 0, stream>>>(g16, b2, deg, csrc, abuf);

    // mean pool (no atomics)
    k_pool<<<NG, 256, 0, stream>>>(abuf, gstart, out);
}